// Round 1
// baseline (214.544 us; speedup 1.0000x reference)
//
#include <hip/hip_runtime.h>
#include <hip/hip_bf16.h>

// Problem constants
#define VV 200000
#define DD 512
#define NN 32768
#define RR 8
#define HH 16
#define KT 4096          // R*D
#define CLAMPV 1000.0f

typedef __attribute__((ext_vector_type(8))) short short8;
typedef __attribute__((ext_vector_type(4))) float f32x4;
typedef __attribute__((ext_vector_type(4))) unsigned int u32x4;

__device__ __forceinline__ unsigned f2bf(float f) {
  union { float f; unsigned u; } v; v.f = f;
  return (v.u + 0x7FFFu + ((v.u >> 16) & 1u)) >> 16;   // RNE f32->bf16
}
__device__ __forceinline__ unsigned pack2(float lo, float hi) {
  return f2bf(lo) | (f2bf(hi) << 16);
}

// ---------------- prep 1: addvec[d] = clip(phase(t))[d] + err[d] -------------
__global__ void prep_phase_k(const float* __restrict__ base_phase,
                             const float* __restrict__ amp,
                             const float* __restrict__ freq,
                             const float* __restrict__ poff,
                             const float* __restrict__ err,
                             const int* __restrict__ tstep,
                             float* __restrict__ addvec) {
  const int d = threadIdx.x;          // 512 threads
  const float t = (float)(*tstep);
  float s = base_phase[d];
#pragma unroll
  for (int h = 0; h < HH; ++h)
    s += amp[h * DD + d] * sinf(freq[h] * t + poff[h]);
  s = fminf(fmaxf(s, -CLAMPV), CLAMPV);
  addvec[d] = s + err[d];
}

// ------------- prep 2: Bt[e][k] = bf16(transform[k][e] * w[k/512]) -----------
// Tiled 64x64 LDS transpose: coalesced reads along e, coalesced writes along k.
__global__ void prep_bt_k(const float* __restrict__ transform,
                          const float* __restrict__ cw,
                          unsigned short* __restrict__ bt) {
  const int bk = blockIdx.x & 63;     // 64 k-tiles
  const int be = blockIdx.x >> 6;     // 8  e-tiles
  const int k0 = bk << 6, e0 = be << 6;
  const float scale = cw[k0 >> 9];    // r = k0/512, uniform per block
  __shared__ float sm[64][65];        // +1 pad
  const int tid = threadIdx.x;        // 256 threads
#pragma unroll
  for (int g = 0; g < 4; ++g) {
    const int c = g * 256 + tid;      // 1024 float4 chunks
    const int kk = c >> 4;
    const int e4 = (c & 15) << 2;
    f32x4 v = *(const f32x4*)(transform + (size_t)(k0 + kk) * DD + e0 + e4);
    sm[kk][e4 + 0] = v[0]; sm[kk][e4 + 1] = v[1];
    sm[kk][e4 + 2] = v[2]; sm[kk][e4 + 3] = v[3];
  }
  __syncthreads();
  const int ee = tid >> 2;
  const int kks = (tid & 3) << 4;
  unsigned short* dst = bt + (size_t)(e0 + ee) * KT + k0 + kks;
#pragma unroll
  for (int half = 0; half < 2; ++half) {
    u32x4 w;
#pragma unroll
    for (int j = 0; j < 4; ++j) {
      const int kk = kks + half * 8 + j * 2;
      w[j] = pack2(sm[kk][ee] * scale, sm[kk + 1][ee] * scale);
    }
    *(u32x4*)(dst + half * 8) = w;
  }
}

// ----------------------------- main fused GEMM -------------------------------
// C[32768x512] = gatherA[32768x4096] x B[4096x512], + base gather + addvec,
// clamp. BM=64, BN=512 (full), BK=64. 512 thr = 8 waves (1x8), wave: 64x64.
__global__ __launch_bounds__(512)
void rw_gemm_k(const float* __restrict__ codebook,
               const int* __restrict__ base_idx,
               const int* __restrict__ ref_idx,
               const unsigned short* __restrict__ bt,
               const float* __restrict__ addvec,
               float* __restrict__ out) {
  __shared__ unsigned short aT[64 * 64];    // [row][k] bf16, swizzled, 8 KB
  __shared__ unsigned short bT[512 * 64];   // [e][k]  bf16, swizzled, 64 KB

  const int tid = threadIdx.x;
  const int lane = tid & 63;
  const int wv = tid >> 6;                  // 0..7 -> col block
  const int mb = blockIdx.x;                // 512 blocks -> rows mb*64..+63

  const f32x4 zero = {0.f, 0.f, 0.f, 0.f};
  f32x4 acc[4][4];
#pragma unroll
  for (int m = 0; m < 4; ++m)
#pragma unroll
    for (int n = 0; n < 4; ++n)
      acc[m][n] = zero;

  // staging mapping: thread -> (row = tid/8, 16B-chunk = tid%8)
  const int arow = tid >> 3;                // 0..63
  const int ac8 = tid & 7;                  // 0..7
  // XOR swizzle; note (g*64+arow)&7 == arow&7, so same swizzle serves B rows
  const int aswz = (ac8 * 16) ^ ((arow & 7) << 4);
  char* aTb = (char*)aT;
  char* bTb = (char*)bT;

  int ridx = 0;

  for (int kt = 0; kt < 64; ++kt) {
    const int r = kt >> 3;
    const int d0 = (kt & 7) << 6;
    if ((kt & 7) == 0)                      // uniform branch: new r-phase
      ridx = ref_idx[(mb * 64 + arow) * RR + r];

    __syncthreads();                        // previous tile's reads done
    {   // stage A: gather 64 rows x 64 k, f32 -> bf16
      const float* src = codebook + (size_t)ridx * DD + d0 + ac8 * 8;
      f32x4 v0 = *(const f32x4*)src;
      f32x4 v1 = *(const f32x4*)(src + 4);
      u32x4 w;
      w[0] = pack2(v0[0], v0[1]);
      w[1] = pack2(v0[2], v0[3]);
      w[2] = pack2(v1[0], v1[1]);
      w[3] = pack2(v1[2], v1[3]);
      *(u32x4*)(aTb + arow * 128 + aswz) = w;
    }
#pragma unroll
    for (int g = 0; g < 8; ++g) {           // stage B: 512 rows x 64 k bf16
      const int erow = g * 64 + arow;
      const unsigned short* src = bt + (size_t)erow * KT + kt * 64 + ac8 * 8;
      u32x4 w = *(const u32x4*)src;
      *(u32x4*)(bTb + erow * 128 + aswz) = w;
    }
    __syncthreads();                        // tile staged

    short8 aF[4][2];
#pragma unroll
    for (int m = 0; m < 4; ++m)
#pragma unroll
      for (int ks = 0; ks < 2; ++ks) {
        const int row = m * 16 + (lane & 15);
        const int kb2 = (ks * 64 + (lane >> 4) * 16) ^ ((row & 7) << 4);
        aF[m][ks] = *(const short8*)(aTb + row * 128 + kb2);
      }
    short8 bF[4][2];
#pragma unroll
    for (int n = 0; n < 4; ++n)
#pragma unroll
      for (int ks = 0; ks < 2; ++ks) {
        const int e = wv * 64 + n * 16 + (lane & 15);
        const int kb2 = (ks * 64 + (lane >> 4) * 16) ^ ((e & 7) << 4);
        bF[n][ks] = *(const short8*)(bTb + e * 128 + kb2);
      }
#pragma unroll
    for (int m = 0; m < 4; ++m)
#pragma unroll
      for (int n = 0; n < 4; ++n)
#pragma unroll
        for (int ks = 0; ks < 2; ++ks)
          acc[m][n] = __builtin_amdgcn_mfma_f32_16x16x32_bf16(
              aF[m][ks], bF[n][ks], acc[m][n], 0, 0, 0);
  }

  // epilogue: + base gather + addvec, clamp, store f32
  // C/D layout: col = lane&15, row = (lane>>4)*4 + reg   [verified m89/m91]
#pragma unroll
  for (int m = 0; m < 4; ++m) {
#pragma unroll
    for (int j = 0; j < 4; ++j) {
      const int row = mb * 64 + m * 16 + (lane >> 4) * 4 + j;
      const int bi = base_idx[row];
      const float* brow = codebook + (size_t)bi * DD;
#pragma unroll
      for (int n = 0; n < 4; ++n) {
        const int col = wv * 64 + n * 16 + (lane & 15);
        float v = acc[m][n][j] + brow[col] + addvec[col];
        v = fminf(fmaxf(v, -CLAMPV), CLAMPV);
        out[(size_t)row * DD + col] = v;
      }
    }
  }
}

extern "C" void kernel_launch(void* const* d_in, const int* in_sizes, int n_in,
                              void* d_out, int out_size, void* d_ws, size_t ws_size,
                              hipStream_t stream) {
  const float* codebook   = (const float*)d_in[0];
  const int*   base_idx   = (const int*)d_in[1];
  const int*   ref_idx    = (const int*)d_in[2];
  const float* transform  = (const float*)d_in[3];
  const float* contrib_w  = (const float*)d_in[4];
  const float* base_phase = (const float*)d_in[5];
  const float* amp        = (const float*)d_in[6];
  const float* freq       = (const float*)d_in[7];
  const float* poff       = (const float*)d_in[8];
  const float* err        = (const float*)d_in[9];
  const int*   tstep      = (const int*)d_in[10];
  float* out = (float*)d_out;

  // ws layout: [0,2048) addvec f32[512]; [2048, 2048+4MB) Bt bf16[512][4096]
  float* addvec = (float*)d_ws;
  unsigned short* bt = (unsigned short*)((char*)d_ws + 2048);

  prep_phase_k<<<1, 512, 0, stream>>>(base_phase, amp, freq, poff, err, tstep, addvec);
  prep_bt_k<<<512, 256, 0, stream>>>(transform, contrib_w, bt);
  rw_gemm_k<<<512, 512, 0, stream>>>(codebook, base_idx, ref_idx, bt, addvec, out);
}

// Round 2
// 209.314 us; speedup vs baseline: 1.0250x; 1.0250x over previous
//
#include <hip/hip_runtime.h>
#include <hip/hip_bf16.h>

// Problem constants
#define VV 200000
#define DD 512
#define NN 32768
#define RR 8
#define HH 16
#define CLAMPV 1000.0f

typedef __attribute__((ext_vector_type(8))) short short8;
typedef __attribute__((ext_vector_type(4))) float f32x4;
typedef __attribute__((ext_vector_type(4))) unsigned int u32x4;

__device__ __forceinline__ unsigned f2bf(float f) {
  union { float f; unsigned u; } v; v.f = f;
  return (v.u + 0x7FFFu + ((v.u >> 16) & 1u)) >> 16;   // RNE f32->bf16
}
__device__ __forceinline__ unsigned pack2(float lo, float hi) {
  return f2bf(lo) | (f2bf(hi) << 16);
}

// ---------------- prep 1: addvec[d] = clip(phase(t))[d] + err[d] -------------
__global__ void prep_phase_k(const float* __restrict__ base_phase,
                             const float* __restrict__ amp,
                             const float* __restrict__ freq,
                             const float* __restrict__ poff,
                             const float* __restrict__ err,
                             const int* __restrict__ tstep,
                             float* __restrict__ addvec) {
  const int d = threadIdx.x;          // 512 threads
  const float t = (float)(*tstep);
  float s = base_phase[d];
#pragma unroll
  for (int h = 0; h < HH; ++h)
    s += amp[h * DD + d] * sinf(freq[h] * t + poff[h]);
  s = fminf(fmaxf(s, -CLAMPV), CLAMPV);
  addvec[d] = s + err[d];
}

// ------------- prep 2: B in MFMA fragment-image layout -----------------------
// bt[((s*32 + g)*64 + l)*8 + j] = bf16( transform[k][e] * w[k/512] )
//   where s = k32-slice (0..127), g = e-group (0..31),
//         e = g*16 + (l&15), k = s*32 + (l>>4)*8 + j.
// This is exactly the verified 16x16x32 B-fragment lane mapping, so the GEMM
// loads B global->reg fully coalesced (1 KB per wave per fragment), no LDS.
__global__ void prep_bt_k(const float* __restrict__ transform,
                          const float* __restrict__ cw,
                          unsigned short* __restrict__ bt) {
  const int bid = blockIdx.x;                    // 1024 blocks x 256 threads
  const int s = bid >> 3;                        // 0..127
  const int g = ((bid & 7) << 2) + (threadIdx.x >> 6);  // 0..31
  const int l = threadIdx.x & 63;
  const int e = g * 16 + (l & 15);
  const int k0 = s * 32 + ((l >> 4) << 3);
  const float scale = cw[s >> 4];                // r = (s*32)/512, uniform
  u32x4 w;
#pragma unroll
  for (int p = 0; p < 4; ++p) {
    const float lo = transform[(size_t)(k0 + 2 * p) * DD + e] * scale;
    const float hi = transform[(size_t)(k0 + 2 * p + 1) * DD + e] * scale;
    w[p] = pack2(lo, hi);
  }
  *(u32x4*)(bt + (((size_t)s * 32 + g) * 64 + l) * 8) = w;
}

// ----------------------------- main fused GEMM -------------------------------
// C[32768x512] = gatherA[32768x4096] x B[4096x512] (+ base + addvec, clamp).
// BM=128, BN=512(full), BK=64. 256 blocks (1/CU), 512 thr = 8 waves, each wave
// owns 128x64 (8x4 grid of 16x16x32). A double-buffered in LDS (16KBx2,
// XOR-swizzled); B fragments straight from L2-resident ws (fragment-image).
__global__ __launch_bounds__(512, 2)
void rw_gemm_k(const float* __restrict__ codebook,
               const int* __restrict__ base_idx,
               const int* __restrict__ ref_idx,
               const unsigned short* __restrict__ bt,
               const float* __restrict__ addvec,
               float* __restrict__ out) {
  __shared__ unsigned short aT[2][128 * 64];     // 16 KB each, swizzled [row][k]

  const int tid = threadIdx.x;
  const int lane = tid & 63;
  const int wv = tid >> 6;                       // 0..7 -> col block (64 cols)
  const int mb = blockIdx.x;                     // rows mb*128 .. +127

  const f32x4 zero = {0.f, 0.f, 0.f, 0.f};
  f32x4 acc[8][4];
#pragma unroll
  for (int m = 0; m < 8; ++m)
#pragma unroll
    for (int n = 0; n < 4; ++n)
      acc[m][n] = zero;

  // A staging: thread -> (row = tid/4, 16 f32 at chunk pair c0=2*(tid&3))
  const int arow = tid >> 2;
  const int aq = tid & 3;
  const unsigned sw = (arow & 7) << 4;
  char* aTb0 = (char*)&aT[0][0];
  char* aTb1 = (char*)&aT[1][0];
  const int wbyte0 = arow * 128 + (((aq * 2) * 16) ^ sw);
  const int wbyte1 = arow * 128 + (((aq * 2) * 16 + 16) ^ sw);

  const int* ridx_base = ref_idx + (size_t)(mb * 128 + arow) * RR;
  int ridx = ridx_base[0];

  // prologue: stage kt=0 into buffer 0
  {
    const float* src = codebook + (size_t)ridx * DD + aq * 16;
    f32x4 a0 = *(const f32x4*)(src);
    f32x4 a1 = *(const f32x4*)(src + 4);
    f32x4 a2 = *(const f32x4*)(src + 8);
    f32x4 a3 = *(const f32x4*)(src + 12);
    u32x4 w0, w1;
    w0[0] = pack2(a0[0], a0[1]); w0[1] = pack2(a0[2], a0[3]);
    w0[2] = pack2(a1[0], a1[1]); w0[3] = pack2(a1[2], a1[3]);
    w1[0] = pack2(a2[0], a2[1]); w1[1] = pack2(a2[2], a2[3]);
    w1[2] = pack2(a3[0], a3[1]); w1[3] = pack2(a3[2], a3[3]);
    *(u32x4*)(aTb0 + wbyte0) = w0;
    *(u32x4*)(aTb0 + wbyte1) = w1;
  }
  __syncthreads();

  // fragment-read constants: row = m*16 + (lane&15); row&7 == lane&7
  const unsigned rsw = (lane & 7) << 4;
  const int rbase = (lane & 15) * 128;
  const int koff = (lane >> 4) * 16;

  for (int kt = 0; kt < 64; ++kt) {
    char* curb = (kt & 1) ? aTb1 : aTb0;
    char* nxtb = (kt & 1) ? aTb0 : aTb1;
    const bool last = (kt == 63);

    // B fragments for this kt: global->reg, coalesced, L2-resident
    short8 bF[4][2];
#pragma unroll
    for (int n = 0; n < 4; ++n)
#pragma unroll
      for (int ks = 0; ks < 2; ++ks) {
        const size_t soff =
            (((size_t)(kt * 2 + ks) * 32 + (wv * 4 + n)) * 64 + lane) * 8;
        bF[n][ks] = *(const short8*)(bt + soff);
      }

    // A gather (f32) for kt+1 — latency hides under this kt's MFMA burst
    f32x4 a0, a1, a2, a3;
    if (!last) {
      const int ktn = kt + 1;
      if ((ktn & 7) == 0) ridx = ridx_base[ktn >> 3];
      const int d0 = (ktn & 7) << 6;
      const float* src = codebook + (size_t)ridx * DD + d0 + aq * 16;
      a0 = *(const f32x4*)(src);
      a1 = *(const f32x4*)(src + 4);
      a2 = *(const f32x4*)(src + 8);
      a3 = *(const f32x4*)(src + 12);
    }

    // compute this kt from LDS A + reg B
#pragma unroll
    for (int ks = 0; ks < 2; ++ks) {
#pragma unroll
      for (int m = 0; m < 8; ++m) {
        const int off = m * 2048 + rbase + ((ks * 64 + koff) ^ rsw);
        const short8 aF = *(const short8*)(curb + off);
#pragma unroll
        for (int n = 0; n < 4; ++n)
          acc[m][n] = __builtin_amdgcn_mfma_f32_16x16x32_bf16(
              aF, bF[n][ks], acc[m][n], 0, 0, 0);
      }
    }

    // convert + write A for kt+1 into the other buffer
    if (!last) {
      u32x4 w0, w1;
      w0[0] = pack2(a0[0], a0[1]); w0[1] = pack2(a0[2], a0[3]);
      w0[2] = pack2(a1[0], a1[1]); w0[3] = pack2(a1[2], a1[3]);
      w1[0] = pack2(a2[0], a2[1]); w1[1] = pack2(a2[2], a2[3]);
      w1[2] = pack2(a3[0], a3[1]); w1[3] = pack2(a3[2], a3[3]);
      *(u32x4*)(nxtb + wbyte0) = w0;
      *(u32x4*)(nxtb + wbyte1) = w1;
    }
    __syncthreads();  // drain is ~free: pending loads are needed next anyway
  }

  // epilogue: + base gather + addvec, clamp, store f32
  // C/D layout: col = lane&15, row = (lane>>4)*4 + reg
#pragma unroll
  for (int m = 0; m < 8; ++m) {
#pragma unroll
    for (int j = 0; j < 4; ++j) {
      const int row = mb * 128 + m * 16 + ((lane >> 4) << 2) + j;
      const int bi = base_idx[row];
      const float* brow = codebook + (size_t)bi * DD;
#pragma unroll
      for (int n = 0; n < 4; ++n) {
        const int col = wv * 64 + n * 16 + (lane & 15);
        float v = acc[m][n][j] + brow[col] + addvec[col];
        v = fminf(fmaxf(v, -CLAMPV), CLAMPV);
        out[(size_t)row * DD + col] = v;
      }
    }
  }
}

extern "C" void kernel_launch(void* const* d_in, const int* in_sizes, int n_in,
                              void* d_out, int out_size, void* d_ws, size_t ws_size,
                              hipStream_t stream) {
  const float* codebook   = (const float*)d_in[0];
  const int*   base_idx   = (const int*)d_in[1];
  const int*   ref_idx    = (const int*)d_in[2];
  const float* transform  = (const float*)d_in[3];
  const float* contrib_w  = (const float*)d_in[4];
  const float* base_phase = (const float*)d_in[5];
  const float* amp        = (const float*)d_in[6];
  const float* freq       = (const float*)d_in[7];
  const float* poff       = (const float*)d_in[8];
  const float* err        = (const float*)d_in[9];
  const int*   tstep      = (const int*)d_in[10];
  float* out = (float*)d_out;

  // ws layout: [0,2048) addvec f32[512]; [2048, 2048+4MB) B fragment-image bf16
  float* addvec = (float*)d_ws;
  unsigned short* bt = (unsigned short*)((char*)d_ws + 2048);

  prep_phase_k<<<1, 512, 0, stream>>>(base_phase, amp, freq, poff, err, tstep, addvec);
  prep_bt_k<<<1024, 256, 0, stream>>>(transform, contrib_w, bt);
  rw_gemm_k<<<256, 512, 0, stream>>>(codebook, base_idx, ref_idx, bt, addvec, out);
}

// Round 3
// 168.243 us; speedup vs baseline: 1.2752x; 1.2441x over previous
//
#include <hip/hip_runtime.h>
#include <hip/hip_bf16.h>

// Problem constants
#define VV 200000
#define DD 512
#define NN 32768
#define RR 8
#define HH 16
#define CLAMPV 1000.0f

typedef __attribute__((ext_vector_type(8))) short short8;
typedef __attribute__((ext_vector_type(4))) float f32x4;
typedef __attribute__((ext_vector_type(4))) unsigned int u32x4;

__device__ __forceinline__ unsigned f2bf(float f) {
  union { float f; unsigned u; } v; v.f = f;
  return (v.u + 0x7FFFu + ((v.u >> 16) & 1u)) >> 16;   // RNE f32->bf16
}
__device__ __forceinline__ unsigned pack2(float lo, float hi) {
  return f2bf(lo) | (f2bf(hi) << 16);
}

// ---------------- prep 1: addvec[d] = clip(phase(t))[d] + err[d] -------------
__global__ void prep_phase_k(const float* __restrict__ base_phase,
                             const float* __restrict__ amp,
                             const float* __restrict__ freq,
                             const float* __restrict__ poff,
                             const float* __restrict__ err,
                             const int* __restrict__ tstep,
                             float* __restrict__ addvec) {
  const int d = threadIdx.x;          // 512 threads
  const float t = (float)(*tstep);
  float s = base_phase[d];
#pragma unroll
  for (int h = 0; h < HH; ++h)
    s += amp[h * DD + d] * sinf(freq[h] * t + poff[h]);
  s = fminf(fmaxf(s, -CLAMPV), CLAMPV);
  addvec[d] = s + err[d];
}

// ------------- prep 2: B in MFMA fragment-image layout -----------------------
// bt[((s*32 + g)*64 + l)*8 + j] = bf16( transform[k][e] * w[k/512] )
//   s = k32-slice (0..127), g = e-group (0..31), e = g*16 + (l&15),
//   k = s*32 + (l>>4)*8 + j  — the verified 16x16x32 B-fragment lane mapping.
__global__ void prep_bt_k(const float* __restrict__ transform,
                          const float* __restrict__ cw,
                          unsigned short* __restrict__ bt) {
  const int bid = blockIdx.x;                    // 1024 blocks x 256 threads
  const int s = bid >> 3;                        // 0..127
  const int g = ((bid & 7) << 2) + (threadIdx.x >> 6);  // 0..31
  const int l = threadIdx.x & 63;
  const int e = g * 16 + (l & 15);
  const int k0 = s * 32 + ((l >> 4) << 3);
  const float scale = cw[s >> 4];                // r = (s*32)/512, uniform
  u32x4 w;
#pragma unroll
  for (int p = 0; p < 4; ++p) {
    const float lo = transform[(size_t)(k0 + 2 * p) * DD + e] * scale;
    const float hi = transform[(size_t)(k0 + 2 * p + 1) * DD + e] * scale;
    w[p] = pack2(lo, hi);
  }
  *(u32x4*)(bt + (((size_t)s * 32 + g) * 64 + l) * 8) = w;
}

// ----------------------------- main fused GEMM -------------------------------
// C[32768x512] = gatherA[32768x4096] x B[4096x512] (+ base + addvec, clamp).
// BM=128, BN=512, BK=64, 256 blocks (1/CU), 8 waves, wave = 128x64 (8x4 frags).
// Counted-vmcnt pipeline: A-gather 2 kt deep (reg-staged, f32->bf16->LDS dbuf,
// XOR-swizzled), B fragments 1 kt deep (reg dbuf, straight from L2-resident
// fragment-image ws). Raw s_barrier (no vmcnt drain) once per kt.
#define VM_WAIT(N) asm volatile("s_waitcnt vmcnt(" #N ")" ::: "memory")
#define LGKM0()    asm volatile("s_waitcnt lgkmcnt(0)" ::: "memory")

#define GSTEP(KT, ASC, ASN, BFC, BFN, ABR, ABW, VMN, DOA, DOB, DOBAR)         \
  {                                                                           \
    if (DOB) { /* B(KT+1) -> BFN, 8x coalesced 1KB dwordx4 */                 \
      const unsigned short* b0 =                                              \
          bt + (size_t)((KT) + 1) * 32768 + wv * 2048 + lane * 8;             \
      _Pragma("unroll") for (int n = 0; n < 4; ++n) {                         \
        BFN[n][0] = *(const short8*)(b0 + n * 512);                           \
        BFN[n][1] = *(const short8*)(b0 + 16384 + n * 512);                   \
      }                                                                       \
    }                                                                         \
    if (DOA) { /* A-gather(KT+2) -> ASN (f32, 16 floats/thread) */            \
      const int kt2 = (KT) + 2;                                               \
      if ((kt2 & 7) == 0) ridx = ridx_base[kt2 >> 3];                         \
      const float* asrc =                                                     \
          codebook + (size_t)ridx * DD + ((kt2 & 7) << 6) + aq * 16;          \
      ASN[0] = *(const f32x4*)(asrc);                                         \
      ASN[1] = *(const f32x4*)(asrc + 4);                                     \
      ASN[2] = *(const f32x4*)(asrc + 8);                                     \
      ASN[3] = *(const f32x4*)(asrc + 12);                                    \
    }                                                                         \
    VM_WAIT(VMN); /* retires A(KT+1) + B(KT); newer stay in flight */         \
    if ((KT) < 63) { /* convert + ds_write A(KT+1) -> ABW */                  \
      u32x4 w0, w1;                                                           \
      w0[0] = pack2(ASC[0][0], ASC[0][1]); w0[1] = pack2(ASC[0][2], ASC[0][3]);\
      w0[2] = pack2(ASC[1][0], ASC[1][1]); w0[3] = pack2(ASC[1][2], ASC[1][3]);\
      w1[0] = pack2(ASC[2][0], ASC[2][1]); w1[1] = pack2(ASC[2][2], ASC[2][3]);\
      w1[2] = pack2(ASC[3][0], ASC[3][1]); w1[3] = pack2(ASC[3][2], ASC[3][3]);\
      *(u32x4*)((ABW) + wbyte0) = w0;                                         \
      *(u32x4*)((ABW) + wbyte1) = w1;                                         \
    }                                                                         \
    __builtin_amdgcn_s_setprio(1);                                            \
    _Pragma("unroll") for (int ks = 0; ks < 2; ++ks) {                        \
      _Pragma("unroll") for (int m = 0; m < 8; ++m) {                         \
        const short8 aFv = *(const short8*)((ABR) + m * 2048 + rbase          \
                                            + ((ks * 64 + koff) ^ rsw));      \
        _Pragma("unroll") for (int n = 0; n < 4; ++n)                         \
          acc[m][n] = __builtin_amdgcn_mfma_f32_16x16x32_bf16(                \
              aFv, BFC[n][ks], acc[m][n], 0, 0, 0);                           \
      }                                                                       \
    }                                                                         \
    __builtin_amdgcn_s_setprio(0);                                            \
    if (DOBAR) { LGKM0(); __builtin_amdgcn_s_barrier(); }                     \
  }

__global__ __launch_bounds__(512, 2)
void rw_gemm_k(const float* __restrict__ codebook,
               const int* __restrict__ base_idx,
               const int* __restrict__ ref_idx,
               const unsigned short* __restrict__ bt,
               const float* __restrict__ addvec,
               float* __restrict__ out) {
  __shared__ unsigned short aT[2][128 * 64];     // 16 KB x2, swizzled [row][k]

  const int tid = threadIdx.x;
  const int lane = tid & 63;
  const int wv = tid >> 6;                       // 0..7 -> col block (64 cols)
  const int mb = blockIdx.x;                     // rows mb*128 .. +127

  const f32x4 zero = {0.f, 0.f, 0.f, 0.f};
  f32x4 acc[8][4];
#pragma unroll
  for (int m = 0; m < 8; ++m)
#pragma unroll
    for (int n = 0; n < 4; ++n)
      acc[m][n] = zero;

  // A staging map: thread -> (row = tid/4, 16 f32 at chunks 2*(tid&3),+1)
  const int arow = tid >> 2;
  const int aq = tid & 3;
  const unsigned sw = (arow & 7) << 4;
  char* ab0 = (char*)&aT[0][0];
  char* ab1 = (char*)&aT[1][0];
  const int wbyte0 = arow * 128 + (((aq * 2) * 16) ^ sw);
  const int wbyte1 = arow * 128 + (((aq * 2) * 16 + 16) ^ sw);

  // fragment-read constants: row = m*16 + (lane&15); row&7 == lane&7
  const unsigned rsw = (lane & 7) << 4;
  const int rbase = (lane & 15) * 128;
  const int koff = (lane >> 4) * 16;

  const int* ridx_base = ref_idx + (size_t)(mb * 128 + arow) * RR;
  int ridx = ridx_base[0];

  f32x4 as0[4], as1[4];
  short8 bF0[4][2], bF1[4][2];

  // ---- prologue: A(0)->LDS buf0, B(0)->bF0, A(1)->as1, one full drain ----
  {
    const float* asrc = codebook + (size_t)ridx * DD + aq * 16;
    as0[0] = *(const f32x4*)(asrc);
    as0[1] = *(const f32x4*)(asrc + 4);
    as0[2] = *(const f32x4*)(asrc + 8);
    as0[3] = *(const f32x4*)(asrc + 12);
    u32x4 w0, w1;
    w0[0] = pack2(as0[0][0], as0[0][1]); w0[1] = pack2(as0[0][2], as0[0][3]);
    w0[2] = pack2(as0[1][0], as0[1][1]); w0[3] = pack2(as0[1][2], as0[1][3]);
    w1[0] = pack2(as0[2][0], as0[2][1]); w1[1] = pack2(as0[2][2], as0[2][3]);
    w1[2] = pack2(as0[3][0], as0[3][1]); w1[3] = pack2(as0[3][2], as0[3][3]);
    *(u32x4*)(ab0 + wbyte0) = w0;
    *(u32x4*)(ab0 + wbyte1) = w1;
  }
  {
    const unsigned short* b0 = bt + wv * 2048 + lane * 8;
#pragma unroll
    for (int n = 0; n < 4; ++n) {
      bF0[n][0] = *(const short8*)(b0 + n * 512);
      bF0[n][1] = *(const short8*)(b0 + 16384 + n * 512);
    }
  }
  {
    const float* asrc = codebook + (size_t)ridx * DD + 64 + aq * 16;  // kt=1
    as1[0] = *(const f32x4*)(asrc);
    as1[1] = *(const f32x4*)(asrc + 4);
    as1[2] = *(const f32x4*)(asrc + 8);
    as1[3] = *(const f32x4*)(asrc + 12);
  }
  __syncthreads();   // one-time full drain, acceptable

  // ---- main pipeline: kt = 0..61 steady, 62/63 tail ----
  for (int k2 = 0; k2 < 31; ++k2) {
    const int kt = k2 * 2;
    GSTEP(kt,     as1, as0, bF0, bF1, ab0, ab1, 12, 1, 1, 1);
    GSTEP(kt + 1, as0, as1, bF1, bF0, ab1, ab0, 12, 1, 1, 1);
  }
  GSTEP(62, as1, as0, bF0, bF1, ab0, ab1, 8, 0, 1, 1);
  GSTEP(63, as0, as1, bF1, bF0, ab1, ab0, 0, 0, 0, 0);

  // epilogue: + base gather + addvec, clamp, store f32
  // C/D layout: col = lane&15, row = (lane>>4)*4 + reg
#pragma unroll
  for (int m = 0; m < 8; ++m) {
#pragma unroll
    for (int j = 0; j < 4; ++j) {
      const int row = mb * 128 + m * 16 + ((lane >> 4) << 2) + j;
      const int bi = base_idx[row];
      const float* brow = codebook + (size_t)bi * DD;
#pragma unroll
      for (int n = 0; n < 4; ++n) {
        const int col = wv * 64 + n * 16 + (lane & 15);
        float v = acc[m][n][j] + brow[col] + addvec[col];
        v = fminf(fmaxf(v, -CLAMPV), CLAMPV);
        out[(size_t)row * DD + col] = v;
      }
    }
  }
}

extern "C" void kernel_launch(void* const* d_in, const int* in_sizes, int n_in,
                              void* d_out, int out_size, void* d_ws, size_t ws_size,
                              hipStream_t stream) {
  const float* codebook   = (const float*)d_in[0];
  const int*   base_idx   = (const int*)d_in[1];
  const int*   ref_idx    = (const int*)d_in[2];
  const float* transform  = (const float*)d_in[3];
  const float* contrib_w  = (const float*)d_in[4];
  const float* base_phase = (const float*)d_in[5];
  const float* amp        = (const float*)d_in[6];
  const float* freq       = (const float*)d_in[7];
  const float* poff       = (const float*)d_in[8];
  const float* err        = (const float*)d_in[9];
  const int*   tstep      = (const int*)d_in[10];
  float* out = (float*)d_out;

  // ws layout: [0,2048) addvec f32[512]; [2048, 2048+4MB) B fragment-image bf16
  float* addvec = (float*)d_ws;
  unsigned short* bt = (unsigned short*)((char*)d_ws + 2048);

  prep_phase_k<<<1, 512, 0, stream>>>(base_phase, amp, freq, poff, err, tstep, addvec);
  prep_bt_k<<<1024, 256, 0, stream>>>(transform, contrib_w, bt);
  rw_gemm_k<<<256, 512, 0, stream>>>(codebook, base_idx, ref_idx, bt, addvec, out);
}